// Round 14
// baseline (193.748 us; speedup 1.0000x reference)
//
#include <hip/hip_runtime.h>

#define T_N   1024
#define B_N   64
#define CIN   32
#define COUT  32
#define MODES 16
#define DT    0.01f
#define PI_F  3.14159265358979323846f
#define W_SCALE 0.613592315154256f   /* 2*pi/(T_N*DT) */
#define W_NYQ  (-314.1592653589793f) /* -pi/DT */

typedef short bf16x8 __attribute__((ext_vector_type(8)));
typedef float f32x4 __attribute__((ext_vector_type(4)));

// swizzled short-column within a 64-row x 32-short tile (16B chunk XOR row&3)
#define SWZ(row, col) (((((col) >> 3) ^ ((row) & 3)) << 3) | ((col) & 7))

__device__ __forceinline__ unsigned short f2bf_rn(float v) {
    unsigned int u = __float_as_uint(v);
    unsigned int rounded = u + 0x7FFFu + ((u >> 16) & 1u);
    return (unsigned short)(rounded >> 16);
}
__device__ __forceinline__ float bf2f(unsigned short s) {
    return __uint_as_float(((unsigned int)s) << 16);
}
__device__ __forceinline__ void bfsplit(float v, short* ph, short* pl) {
    unsigned short h = f2bf_rn(v);
    unsigned short lo = f2bf_rn(v - bf2f(h));
    *ph = (short)h; *pl = (short)lo;
}

// ---------------------------------------------------------------------------
// Radix-2 Stockham FFT, length 1024, LDS twiddle table.
// ---------------------------------------------------------------------------
template <int SIGN>
__device__ __forceinline__ void fft1024(float2* A, float2* B, const float2* TW, int tid) {
    float2* src = A;
    float2* dst = B;
    int m = 1;
#pragma unroll
    for (int s = 0; s < 10; ++s) {
        __syncthreads();
#pragma unroll
        for (int r = 0; r < 2; ++r) {
            int idx = tid + (r << 8);
            int k = idx & (m - 1);
            int j = idx >> s;
            float2 c0 = src[k + j * m];
            float2 c1 = src[k + j * m + 512];
            float2 w = TW[(j << s)];
            float ex = c0.x - c1.x, ey = c0.y - c1.y;
            dst[k + 2 * j * m]     = make_float2(c0.x + c1.x, c0.y + c1.y);
            dst[k + 2 * j * m + m] = make_float2(w.x * ex - w.y * ey, w.x * ey + w.y * ex);
        }
        float2* t = src; src = dst; dst = t;
        m <<= 1;
    }
    __syncthreads();
}

template <int SIGN>
__device__ __forceinline__ void build_tw(float2* TW, int tid) {
#pragma unroll
    for (int r = 0; r < 2; ++r) {
        int a = tid + (r << 8);
        float sn, cs;
        __sincosf((float)SIGN * PI_F * (float)a * (1.0f / 512.0f), &sn, &cs);
        TW[a] = make_float2(cs, sn);
    }
}

// ---------------------------------------------------------------------------
// forward FFT + fused split-bf16 conversion (k_conv merged: alpha is in LDS,
// x=0 column's imag slot carries Re(alpha[512]) straight from A[512]).
// ---------------------------------------------------------------------------
__global__ __launch_bounds__(256) void k_fft_fwd(const float* __restrict__ x,
                                                 float2* __restrict__ alpha,
                                                 short* __restrict__ aHi,
                                                 short* __restrict__ aLo) {
    __shared__ float2 A[1024];
    __shared__ float2 Bb[1024];
    __shared__ float2 TW[512];
    int row = blockIdx.x;
    int tid = threadIdx.x;
    build_tw<-1>(TW, tid);
    const float* xr = x + (size_t)row * T_N;
#pragma unroll
    for (int r = 0; r < 4; ++r) {
        int j = tid + (r << 8);
        A[j] = make_float2(xr[j], 0.0f);
    }
    fft1024<-1>(A, Bb, TW, tid);
    float2* outp = alpha + (size_t)row * T_N;
#pragma unroll
    for (int r = 0; r < 4; ++r) {
        int j = tid + (r << 8);
        outp[j] = A[j];
    }
    size_t base = (size_t)row * 1024;
#pragma unroll
    for (int rr_ = 0; rr_ < 2; ++rr_) {
        int xj = tid + (rr_ << 8);        // 0..511
        float2 v = A[xj];
        float aR = v.x;
        float aI = (xj == 0) ? A[512].x : v.y;
        short h0, l0, h1, l1;
        bfsplit(aR, &h0, &l0);
        bfsplit(aI, &h1, &l1);
        aHi[base + xj * 2]     = h0;
        aHi[base + xj * 2 + 1] = h1;
        aLo[base + xj * 2]     = l0;
        aLo[base + xj * 2 + 1] = l1;
    }
}

// ---------------------------------------------------------------------------
// transpose alpha[(b*CIN+i)][x] -> alphaT[i][x][b]   (feeds k_out1 only)
// ---------------------------------------------------------------------------
__global__ __launch_bounds__(256) void k_transpose_a(const float2* __restrict__ alpha,
                                                     float2* __restrict__ alphaT) {
    __shared__ float2 T[32 * 66];
    int blk = blockIdx.x;
    int i = blk >> 5, xt = blk & 31;
    int tid = threadIdx.x;
#pragma unroll
    for (int r = 0; r < 8; ++r) {
        int e = tid + (r << 8);
        int xx = e & 31, b = e >> 5;
        T[xx * 66 + b] = alpha[((size_t)(b * CIN + i)) * T_N + xt * 32 + xx];
    }
    __syncthreads();
#pragma unroll
    for (int r = 0; r < 8; ++r) {
        int e = tid + (r << 8);
        int b = e & 63, xx = e >> 6;
        alphaT[((size_t)i * T_N + xt * 32 + xx) * B_N + b] = T[xx * 66 + b];
    }
}

// ---------------------------------------------------------------------------
// out1: per-frequency mixing (unchanged — works).
// ---------------------------------------------------------------------------
__global__ __launch_bounds__(256) void k_out1(const float4* __restrict__ alphaT4,
                                              const float* __restrict__ pr,
                                              const float* __restrict__ pim,
                                              const float* __restrict__ rr,
                                              const float* __restrict__ ri,
                                              float2* __restrict__ out1tmp) {
    __shared__ float sARe[32 * 64];
    __shared__ float sAIm[32 * 64];
    __shared__ float2 Hs[32 * 32];
    int x = blockIdx.x;
    int tid = threadIdx.x;

#pragma unroll
    for (int r = 0; r < 4; ++r) {
        int e = tid + (r << 8);
        int i = e >> 5, bp = e & 31;
        float4 v = alphaT4[((size_t)i * T_N + x) * (B_N / 2) + bp];
        *(float2*)&sARe[i * 64 + bp * 2] = make_float2(v.x, v.z);
        *(float2*)&sAIm[i * 64 + bp * 2] = make_float2(v.y, v.w);
    }

    int fx = x - ((x >= 512) ? 1024 : 0);
    float w = (float)fx * W_SCALE;
#pragma unroll
    for (int r = 0; r < 4; ++r) {
        int e = tid + (r << 8);
        int i = e >> 5, o = e & 31;
        int base = (i * COUT + o) * MODES;
        float hr = 0.f, hi = 0.f;
#pragma unroll
        for (int k = 0; k < MODES; ++k) {
            float a = pr[base + k], bI = pim[base + k];
            float d = w - bI;
            float inv = 1.0f / (a * a + d * d);
            float vR = -a * inv, vI = -d * inv;
            float sR = rr[base + k], sI = ri[base + k];
            hr += sR * vR - sI * vI;
            hi += sR * vI + sI * vR;
        }
        Hs[i * 32 + o] = make_float2(hr, hi);
    }
    __syncthreads();

    int o = tid & 31, bg = tid >> 5;
    float accR[8] = {}, accI[8] = {};
#pragma unroll 2
    for (int i = 0; i < CIN; ++i) {
        float2 h = Hs[i * 32 + o];
        float4 ar0 = *(const float4*)&sARe[i * 64 + bg * 8];
        float4 ar1 = *(const float4*)&sARe[i * 64 + bg * 8 + 4];
        float4 ai0 = *(const float4*)&sAIm[i * 64 + bg * 8];
        float4 ai1 = *(const float4*)&sAIm[i * 64 + bg * 8 + 4];
        float aR[8] = {ar0.x, ar0.y, ar0.z, ar0.w, ar1.x, ar1.y, ar1.z, ar1.w};
        float aI[8] = {ai0.x, ai0.y, ai0.z, ai0.w, ai1.x, ai1.y, ai1.z, ai1.w};
#pragma unroll
        for (int bb = 0; bb < 8; ++bb) {
            accR[bb] += aR[bb] * h.x - aI[bb] * h.y;
            accI[bb] += aR[bb] * h.y + aI[bb] * h.x;
        }
    }
#pragma unroll
    for (int bb = 0; bb < 8; ++bb) {
        out1tmp[(size_t)x * 2048 + (bg * 8 + bb) * 32 + o] =
            make_float2(accR[bb], accI[bb]);
    }
}

// ---------------------------------------------------------------------------
// out2 MFMA + XOR-swizzled LDS tiles (conflict fix).
// partial[chunk=(i*2+xh)][b][n] fp32, 64 chunks.
// ---------------------------------------------------------------------------
#define ABROW 40   /* shorts per LDS row: 32 data + 8 pad (80B) */
__global__ __launch_bounds__(256) void k_out2m(const short* __restrict__ aHi,
                                               const short* __restrict__ aLo,
                                               const float* __restrict__ pr,
                                               const float* __restrict__ pim,
                                               const float* __restrict__ rr,
                                               const float* __restrict__ ri,
                                               float* __restrict__ partial) {
    __shared__ short sAh[64 * ABROW], sAl[64 * ABROW];
    __shared__ short sBh[64 * ABROW], sBl[64 * ABROW];
    __shared__ float sPol[4][32];

    const int nb = blockIdx.x, xh = blockIdx.y, i = blockIdx.z;
    const int tid = threadIdx.x;
    const int w = tid >> 6, l = tid & 63;
    const int r = l & 15, hg = l >> 4;
    const int rcol = (hg ^ (r & 3)) << 3;        // swizzled read column

    if (tid < 32) {
        int o = nb * 2 + (tid >> 4), k = tid & 15;
        int pidx = (i * COUT + o) * MODES + k;
        sPol[0][tid] = pr[pidx]; sPol[1][tid] = pim[pidx];
        sPol[2][tid] = rr[pidx]; sPol[3][tid] = ri[pidx];
    }
    __syncthreads();

    f32x4 acc0 = {0.f, 0.f, 0.f, 0.f};
    f32x4 acc1 = {0.f, 0.f, 0.f, 0.f};
    f32x4 acc2 = {0.f, 0.f, 0.f, 0.f};
    f32x4 acc3 = {0.f, 0.f, 0.f, 0.f};

    const int sb = tid >> 2;                          // staging row (b)
    const int gcol = (tid & 3) * 8;                   // global col (shorts)
    const int lcol = (((tid & 3) ^ (sb & 3)) << 3);   // swizzled LDS col
    const size_t abase = ((size_t)sb * CIN + i) * 1024 + (size_t)xh * 512;

    for (int ks = 0; ks < 16; ++ks) {
        __syncthreads();
        *(float4*)&sAh[sb * ABROW + lcol] = *(const float4*)&aHi[abase + ks * 32 + gcol];
        *(float4*)&sAl[sb * ABROW + lcol] = *(const float4*)&aLo[abase + ks * 32 + gcol];
#pragma unroll
        for (int qq = 0; qq < 2; ++qq) {
            int q = (qq << 8) + tid;          // consecutive lanes -> consecutive ok
            int xl = q >> 5, ok = q & 31;
            int xg = xh * 256 + ks * 16 + xl;
            float a = sPol[0][ok], bI = sPol[1][ok];
            float sR = sPol[2][ok], sI = sPol[3][ok];
            float c1r, c1i, c2r, c2i;
            if (xg == 0) {
                float s1 = a * a + bI * bI;
                float q1r = a / s1, q1i = -bI / s1;
                c1r = sR * q1r - sI * q1i;
                c1i = sR * q1i + sI * q1r;
                float dr = -a, di = W_NYQ - bI;
                float s2 = dr * dr + di * di;
                float q2r = dr / s2, q2i = -di / s2;
                c2r = -(sR * q2r - sI * q2i);
                c2i = -(sR * q2i + sI * q2r);
            } else {
                float wv = (float)xg * W_SCALE;
                float denr = a * a - bI * bI + wv * wv;
                float deni = 2.0f * a * bI;
                float s = denr * denr + deni * deni;
                float qr = denr / s, qi = -deni / s;
                float prr = a * sR - bI * sI;
                float pri = a * sI + bI * sR;
                c1r = 2.0f * (prr * qr - pri * qi);
                c1i = 2.0f * (prr * qi + pri * qr);
                float rqr = sR * qr - sI * qi;
                float rqi = sR * qi + sI * qr;
                c2r = -2.0f * wv * rqr;
                c2i = -2.0f * wv * rqi;
            }
            int r0 = ok * 2, r1 = ok * 2 + 1, c0 = xl * 2;
            int p0 = r0 * ABROW + SWZ(r0, c0);
            int p1 = r1 * ABROW + SWZ(r1, c0);
            bfsplit(c1r, &sBh[p0],     &sBl[p0]);
            bfsplit(c2r, &sBh[p0 + 1], &sBl[p0 + 1]);
            bfsplit(c1i, &sBh[p1],     &sBl[p1]);
            bfsplit(c2i, &sBh[p1 + 1], &sBl[p1 + 1]);
        }
        __syncthreads();

        bf16x8 bh = *(bf16x8*)&sBh[(w * 16 + r) * ABROW + rcol];
        bf16x8 bl = *(bf16x8*)&sBl[(w * 16 + r) * ABROW + rcol];
        {
            bf16x8 ah = *(bf16x8*)&sAh[(0 * 16 + r) * ABROW + rcol];
            bf16x8 al = *(bf16x8*)&sAl[(0 * 16 + r) * ABROW + rcol];
            acc0 = __builtin_amdgcn_mfma_f32_16x16x32_bf16(ah, bh, acc0, 0, 0, 0);
            acc0 = __builtin_amdgcn_mfma_f32_16x16x32_bf16(al, bh, acc0, 0, 0, 0);
            acc0 = __builtin_amdgcn_mfma_f32_16x16x32_bf16(ah, bl, acc0, 0, 0, 0);
        }
        {
            bf16x8 ah = *(bf16x8*)&sAh[(1 * 16 + r) * ABROW + rcol];
            bf16x8 al = *(bf16x8*)&sAl[(1 * 16 + r) * ABROW + rcol];
            acc1 = __builtin_amdgcn_mfma_f32_16x16x32_bf16(ah, bh, acc1, 0, 0, 0);
            acc1 = __builtin_amdgcn_mfma_f32_16x16x32_bf16(al, bh, acc1, 0, 0, 0);
            acc1 = __builtin_amdgcn_mfma_f32_16x16x32_bf16(ah, bl, acc1, 0, 0, 0);
        }
        {
            bf16x8 ah = *(bf16x8*)&sAh[(2 * 16 + r) * ABROW + rcol];
            bf16x8 al = *(bf16x8*)&sAl[(2 * 16 + r) * ABROW + rcol];
            acc2 = __builtin_amdgcn_mfma_f32_16x16x32_bf16(ah, bh, acc2, 0, 0, 0);
            acc2 = __builtin_amdgcn_mfma_f32_16x16x32_bf16(al, bh, acc2, 0, 0, 0);
            acc2 = __builtin_amdgcn_mfma_f32_16x16x32_bf16(ah, bl, acc2, 0, 0, 0);
        }
        {
            bf16x8 ah = *(bf16x8*)&sAh[(3 * 16 + r) * ABROW + rcol];
            bf16x8 al = *(bf16x8*)&sAl[(3 * 16 + r) * ABROW + rcol];
            acc3 = __builtin_amdgcn_mfma_f32_16x16x32_bf16(ah, bh, acc3, 0, 0, 0);
            acc3 = __builtin_amdgcn_mfma_f32_16x16x32_bf16(al, bh, acc3, 0, 0, 0);
            acc3 = __builtin_amdgcn_mfma_f32_16x16x32_bf16(ah, bl, acc3, 0, 0, 0);
        }
    }

    int chunk = i * 2 + xh;
    int n = nb * 64 + w * 16 + r;
    float* dst = partial + (size_t)chunk * (B_N * 1024) + n;
#pragma unroll
    for (int reg = 0; reg < 4; ++reg) {
        dst[(0 * 16 + hg * 4 + reg) * 1024] = acc0[reg];
        dst[(1 * 16 + hg * 4 + reg) * 1024] = acc1[reg];
        dst[(2 * 16 + hg * 4 + reg) * 1024] = acc2[reg];
        dst[(3 * 16 + hg * 4 + reg) * 1024] = acc3[reg];
    }
}

// ---------------------------------------------------------------------------
// reduce 64 partials into split-bf16 A for x2: aXh/aXl[b][ck]
// ---------------------------------------------------------------------------
__global__ __launch_bounds__(256) void k_reduce(const float4* __restrict__ p,
                                                short4* __restrict__ aXh,
                                                short4* __restrict__ aXl,
                                                int nchunk) {
    int f = blockIdx.x * 256 + threadIdx.x;   // 16384 float4s
    float4 s = make_float4(0.f, 0.f, 0.f, 0.f);
    for (int c = 0; c < nchunk; ++c) {
        float4 v = p[(size_t)c * 16384 + f];
        s.x += v.x; s.y += v.y; s.z += v.z; s.w += v.w;
    }
    short4 h, l;
    bfsplit(s.x, &h.x, &l.x);
    bfsplit(s.y, &h.y, &l.y);
    bfsplit(s.z, &h.z, &l.z);
    bfsplit(s.w, &h.w, &l.w);
    aXh[f] = h;
    aXl[f] = l;
}

// ---------------------------------------------------------------------------
// transpose out1tmp[x][bo] -> out1T[bo][x]
// ---------------------------------------------------------------------------
__global__ __launch_bounds__(256) void k_transpose_o1(const float2* __restrict__ out1tmp,
                                                      float2* __restrict__ out1T) {
    __shared__ float2 T[64 * 33];
    int blk = blockIdx.x;
    int bot = blk >> 5, xt = blk & 31;
    int tid = threadIdx.x;
#pragma unroll
    for (int r = 0; r < 8; ++r) {
        int e = tid + (r << 8);
        int j = e & 63, xr = e >> 6;
        T[j * 33 + xr] = out1tmp[((size_t)(xt * 32 + xr)) * 2048 + bot * 64 + j];
    }
    __syncthreads();
#pragma unroll
    for (int r = 0; r < 8; ++r) {
        int e = tid + (r << 8);
        int xx = e & 31, j = e >> 5;
        out1T[((size_t)(bot * 64 + j)) * T_N + xt * 32 + xx] = T[j * 33 + xx];
    }
}

__global__ __launch_bounds__(256) void k_ifft(const float2* __restrict__ out1T,
                                              float* __restrict__ outp) {
    __shared__ float2 A[1024];
    __shared__ float2 Bb[1024];
    __shared__ float2 TW[512];
    int row = blockIdx.x;
    int tid = threadIdx.x;
    build_tw<1>(TW, tid);
    const float2* src = out1T + (size_t)row * T_N;
#pragma unroll
    for (int r = 0; r < 4; ++r) {
        int j = tid + (r << 8);
        A[j] = src[j];
    }
    fft1024<1>(A, Bb, TW, tid);
    float* dst = outp + (size_t)row * T_N;
    const float inv_n = 1.0f / (float)T_N;
#pragma unroll
    for (int r = 0; r < 4; ++r) {
        int j = tid + (r << 8);
        dst[j] = A[j].x * inv_n;
    }
}

// ---------------------------------------------------------------------------
// x2 MFMA + XOR-swizzled LDS tiles. Grid dim3(zb:16, o:32).
// ---------------------------------------------------------------------------
__global__ __launch_bounds__(256) void k_x2m(const short* __restrict__ aXh,
                                             const short* __restrict__ aXl,
                                             const float* __restrict__ pr,
                                             const float* __restrict__ pim,
                                             float* __restrict__ outp) {
    __shared__ short sAh[64 * ABROW], sAl[64 * ABROW];
    __shared__ short sBh[64 * ABROW], sBl[64 * ABROW];
    __shared__ float s_pr[512], s_pim[512];

    const int zb = blockIdx.x, o = blockIdx.y;
    const int tid = threadIdx.x;
    const int w = tid >> 6, l = tid & 63;
    const int r = l & 15, hg = l >> 4;
    const int rcol = (hg ^ (r & 3)) << 3;        // swizzled read column

#pragma unroll
    for (int rr_ = 0; rr_ < 2; ++rr_) {
        int cm = tid + (rr_ << 8);           // 0..511
        int c = cm >> 4, m = cm & 15;
        int pidx = (c * COUT + o) * MODES + m;
        s_pr[cm] = pr[pidx];
        s_pim[cm] = pim[pidx];
    }
    __syncthreads();

    f32x4 acc0 = {0.f, 0.f, 0.f, 0.f};
    f32x4 acc1 = {0.f, 0.f, 0.f, 0.f};
    f32x4 acc2 = {0.f, 0.f, 0.f, 0.f};
    f32x4 acc3 = {0.f, 0.f, 0.f, 0.f};

    const int sb = tid >> 2;                          // staging row (b)
    const int gcol = (tid & 3) * 8;                   // global col (shorts)
    const int lcol = (((tid & 3) ^ (sb & 3)) << 3);   // swizzled LDS col
    const float z0f = (float)(zb * 64);

    for (int ks = 0; ks < 32; ++ks) {
        __syncthreads();
        *(float4*)&sAh[sb * ABROW + lcol] = *(const float4*)&aXh[sb * 1024 + ks * 32 + gcol];
        *(float4*)&sAl[sb * ABROW + lcol] = *(const float4*)&aXl[sb * 1024 + ks * 32 + gcol];
#pragma unroll
        for (int qq = 0; qq < 4; ++qq) {
            int slot = (qq << 8) + tid;      // 0..1023
            int z = slot & 63, cml = slot >> 6;
            int cm = ks * 16 + cml;
            float gr = s_pr[cm], gi = s_pim[cm];
            float tz = (z0f + (float)z) * DT;
            float er = __expf(gr * tz);
            float sn, cn;
            __sincosf(gi * tz, &sn, &cn);
            int pz = z * ABROW + SWZ(z, cml * 2);
            bfsplit(er * cn,  &sBh[pz],     &sBl[pz]);
            bfsplit(-er * sn, &sBh[pz + 1], &sBl[pz + 1]);
        }
        __syncthreads();

        bf16x8 bh = *(bf16x8*)&sBh[(w * 16 + r) * ABROW + rcol];
        bf16x8 bl = *(bf16x8*)&sBl[(w * 16 + r) * ABROW + rcol];
        {
            bf16x8 ah = *(bf16x8*)&sAh[(0 * 16 + r) * ABROW + rcol];
            bf16x8 al = *(bf16x8*)&sAl[(0 * 16 + r) * ABROW + rcol];
            acc0 = __builtin_amdgcn_mfma_f32_16x16x32_bf16(ah, bh, acc0, 0, 0, 0);
            acc0 = __builtin_amdgcn_mfma_f32_16x16x32_bf16(al, bh, acc0, 0, 0, 0);
            acc0 = __builtin_amdgcn_mfma_f32_16x16x32_bf16(ah, bl, acc0, 0, 0, 0);
        }
        {
            bf16x8 ah = *(bf16x8*)&sAh[(1 * 16 + r) * ABROW + rcol];
            bf16x8 al = *(bf16x8*)&sAl[(1 * 16 + r) * ABROW + rcol];
            acc1 = __builtin_amdgcn_mfma_f32_16x16x32_bf16(ah, bh, acc1, 0, 0, 0);
            acc1 = __builtin_amdgcn_mfma_f32_16x16x32_bf16(al, bh, acc1, 0, 0, 0);
            acc1 = __builtin_amdgcn_mfma_f32_16x16x32_bf16(ah, bl, acc1, 0, 0, 0);
        }
        {
            bf16x8 ah = *(bf16x8*)&sAh[(2 * 16 + r) * ABROW + rcol];
            bf16x8 al = *(bf16x8*)&sAl[(2 * 16 + r) * ABROW + rcol];
            acc2 = __builtin_amdgcn_mfma_f32_16x16x32_bf16(ah, bh, acc2, 0, 0, 0);
            acc2 = __builtin_amdgcn_mfma_f32_16x16x32_bf16(al, bh, acc2, 0, 0, 0);
            acc2 = __builtin_amdgcn_mfma_f32_16x16x32_bf16(ah, bl, acc2, 0, 0, 0);
        }
        {
            bf16x8 ah = *(bf16x8*)&sAh[(3 * 16 + r) * ABROW + rcol];
            bf16x8 al = *(bf16x8*)&sAl[(3 * 16 + r) * ABROW + rcol];
            acc3 = __builtin_amdgcn_mfma_f32_16x16x32_bf16(ah, bh, acc3, 0, 0, 0);
            acc3 = __builtin_amdgcn_mfma_f32_16x16x32_bf16(al, bh, acc3, 0, 0, 0);
            acc3 = __builtin_amdgcn_mfma_f32_16x16x32_bf16(ah, bl, acc3, 0, 0, 0);
        }
    }

    const float inv_n = 1.0f / (float)T_N;
    size_t base = (size_t)o * T_N + zb * 64 + w * 16 + r;
#pragma unroll
    for (int reg = 0; reg < 4; ++reg) {
        size_t i0 = base + (size_t)(0 * 16 + hg * 4 + reg) * (COUT * T_N);
        size_t i1 = base + (size_t)(1 * 16 + hg * 4 + reg) * (COUT * T_N);
        size_t i2 = base + (size_t)(2 * 16 + hg * 4 + reg) * (COUT * T_N);
        size_t i3 = base + (size_t)(3 * 16 + hg * 4 + reg) * (COUT * T_N);
        outp[i0] += acc0[reg] * inv_n;
        outp[i1] += acc1[reg] * inv_n;
        outp[i2] += acc2[reg] * inv_n;
        outp[i3] += acc3[reg] * inv_n;
    }
}

// ---------------------------------------------------------------------------
extern "C" void kernel_launch(void* const* d_in, const int* in_sizes, int n_in,
                              void* d_out, int out_size, void* d_ws, size_t ws_size,
                              hipStream_t stream) {
    const float* x   = (const float*)d_in[0];
    const float* pr  = (const float*)d_in[2];
    const float* pim = (const float*)d_in[3];
    const float* rr  = (const float*)d_in[4];
    const float* ri  = (const float*)d_in[5];
    float* outp = (float*)d_out;

    char* ws = (char*)d_ws;
    const size_t MB = 1024 * 1024;
    const size_t KB = 1024;
    float2* alpha   = (float2*)ws;                     // [0,16M)
    float2* alphaT  = (float2*)(ws + 16 * MB);         // [16M,32M)
    short*  aXh     = (short*)(ws + 32 * MB);          // [32M,+128K)
    short*  aXl     = (short*)(ws + 32 * MB + 128 * KB); // [+128K,+256K)
    short*  aHi     = (short*)(ws + 33 * MB);          // [33M,37M)
    short*  aLo     = (short*)(ws + 37 * MB);          // [37M,41M)
    float*  o2part;
    if (ws_size >= (size_t)(57 * MB)) {
        o2part = (float*)(ws + 41 * MB);               // [41M,57M): 64 x 256KB
    } else {
        o2part = (float*)ws;                           // region A (alpha dead)
    }
    float2* out1tmp = (float2*)ws;                     // region A (after reduce)
    float2* out1T   = (float2*)(ws + 16 * MB);         // region B (alphaT dead)

    k_fft_fwd     <<<B_N * CIN, 256, 0, stream>>>(x, alpha, aHi, aLo);
    k_transpose_a <<<CIN * 32, 256, 0, stream>>>(alpha, alphaT);
    k_out2m       <<<dim3(16, 2, 32), 256, 0, stream>>>(aHi, aLo,
                                                        pr, pim, rr, ri, o2part);
    k_reduce      <<<64, 256, 0, stream>>>((const float4*)o2part,
                                           (short4*)aXh, (short4*)aXl, 64);
    k_out1        <<<T_N, 256, 0, stream>>>((const float4*)alphaT,
                                            pr, pim, rr, ri, out1tmp);
    k_transpose_o1<<<32 * 32, 256, 0, stream>>>(out1tmp, out1T);
    k_ifft        <<<B_N * COUT, 256, 0, stream>>>(out1T, outp);
    k_x2m         <<<dim3(16, 32), 256, 0, stream>>>(aXh, aXl, pr, pim, outp);
}

// Round 15
// 159.163 us; speedup vs baseline: 1.2173x; 1.2173x over previous
//
#include <hip/hip_runtime.h>

#define T_N   1024
#define B_N   64
#define CIN   32
#define COUT  32
#define MODES 16
#define DT    0.01f
#define PI_F  3.14159265358979323846f
#define W_SCALE 0.613592315154256f   /* 2*pi/(T_N*DT) */
#define W_NYQ  (-314.1592653589793f) /* -pi/DT */

typedef short bf16x8 __attribute__((ext_vector_type(8)));
typedef float f32x4 __attribute__((ext_vector_type(4)));

__device__ __forceinline__ unsigned short f2bf_rn(float v) {
    unsigned int u = __float_as_uint(v);
    unsigned int rounded = u + 0x7FFFu + ((u >> 16) & 1u);
    return (unsigned short)(rounded >> 16);
}
__device__ __forceinline__ float bf2f(unsigned short s) {
    return __uint_as_float(((unsigned int)s) << 16);
}
__device__ __forceinline__ void bfsplit(float v, short* ph, short* pl) {
    unsigned short h = f2bf_rn(v);
    unsigned short lo = f2bf_rn(v - bf2f(h));
    *ph = (short)h; *pl = (short)lo;
}

// ---------------------------------------------------------------------------
// Radix-2 Stockham FFT, length 1024, LDS twiddle table.
// ---------------------------------------------------------------------------
template <int SIGN>
__device__ __forceinline__ void fft1024(float2* A, float2* B, const float2* TW, int tid) {
    float2* src = A;
    float2* dst = B;
    int m = 1;
#pragma unroll
    for (int s = 0; s < 10; ++s) {
        __syncthreads();
#pragma unroll
        for (int r = 0; r < 2; ++r) {
            int idx = tid + (r << 8);
            int k = idx & (m - 1);
            int j = idx >> s;
            float2 c0 = src[k + j * m];
            float2 c1 = src[k + j * m + 512];
            float2 w = TW[(j << s)];
            float ex = c0.x - c1.x, ey = c0.y - c1.y;
            dst[k + 2 * j * m]     = make_float2(c0.x + c1.x, c0.y + c1.y);
            dst[k + 2 * j * m + m] = make_float2(w.x * ex - w.y * ey, w.x * ey + w.y * ex);
        }
        float2* t = src; src = dst; dst = t;
        m <<= 1;
    }
    __syncthreads();
}

template <int SIGN>
__device__ __forceinline__ void build_tw(float2* TW, int tid) {
#pragma unroll
    for (int r = 0; r < 2; ++r) {
        int a = tid + (r << 8);
        float sn, cs;
        __sincosf((float)SIGN * PI_F * (float)a * (1.0f / 512.0f), &sn, &cs);
        TW[a] = make_float2(cs, sn);
    }
}

// ---------------------------------------------------------------------------
// forward FFT + fused split-bf16 conversion.
// ---------------------------------------------------------------------------
__global__ __launch_bounds__(256) void k_fft_fwd(const float* __restrict__ x,
                                                 float2* __restrict__ alpha,
                                                 short* __restrict__ aHi,
                                                 short* __restrict__ aLo) {
    __shared__ float2 A[1024];
    __shared__ float2 Bb[1024];
    __shared__ float2 TW[512];
    int row = blockIdx.x;
    int tid = threadIdx.x;
    build_tw<-1>(TW, tid);
    const float* xr = x + (size_t)row * T_N;
#pragma unroll
    for (int r = 0; r < 4; ++r) {
        int j = tid + (r << 8);
        A[j] = make_float2(xr[j], 0.0f);
    }
    fft1024<-1>(A, Bb, TW, tid);
    float2* outp = alpha + (size_t)row * T_N;
#pragma unroll
    for (int r = 0; r < 4; ++r) {
        int j = tid + (r << 8);
        outp[j] = A[j];
    }
    size_t base = (size_t)row * 1024;
#pragma unroll
    for (int rr_ = 0; rr_ < 2; ++rr_) {
        int xj = tid + (rr_ << 8);        // 0..511
        float2 v = A[xj];
        float aR = v.x;
        float aI = (xj == 0) ? A[512].x : v.y;
        short h0, l0, h1, l1;
        bfsplit(aR, &h0, &l0);
        bfsplit(aI, &h1, &l1);
        aHi[base + xj * 2]     = h0;
        aHi[base + xj * 2 + 1] = h1;
        aLo[base + xj * 2]     = l0;
        aLo[base + xj * 2 + 1] = l1;
    }
}

// ---------------------------------------------------------------------------
// transpose alpha[(b*CIN+i)][x] -> alphaT[i][x][b]   (feeds k_out1 only)
// ---------------------------------------------------------------------------
__global__ __launch_bounds__(256) void k_transpose_a(const float2* __restrict__ alpha,
                                                     float2* __restrict__ alphaT) {
    __shared__ float2 T[32 * 66];
    int blk = blockIdx.x;
    int i = blk >> 5, xt = blk & 31;
    int tid = threadIdx.x;
#pragma unroll
    for (int r = 0; r < 8; ++r) {
        int e = tid + (r << 8);
        int xx = e & 31, b = e >> 5;
        T[xx * 66 + b] = alpha[((size_t)(b * CIN + i)) * T_N + xt * 32 + xx];
    }
    __syncthreads();
#pragma unroll
    for (int r = 0; r < 8; ++r) {
        int e = tid + (r << 8);
        int b = e & 63, xx = e >> 6;
        alphaT[((size_t)i * T_N + xt * 32 + xx) * B_N + b] = T[xx * 66 + b];
    }
}

// ---------------------------------------------------------------------------
// out1: per-frequency mixing (unchanged — works).
// ---------------------------------------------------------------------------
__global__ __launch_bounds__(256) void k_out1(const float4* __restrict__ alphaT4,
                                              const float* __restrict__ pr,
                                              const float* __restrict__ pim,
                                              const float* __restrict__ rr,
                                              const float* __restrict__ ri,
                                              float2* __restrict__ out1tmp) {
    __shared__ float sARe[32 * 64];
    __shared__ float sAIm[32 * 64];
    __shared__ float2 Hs[32 * 32];
    int x = blockIdx.x;
    int tid = threadIdx.x;

#pragma unroll
    for (int r = 0; r < 4; ++r) {
        int e = tid + (r << 8);
        int i = e >> 5, bp = e & 31;
        float4 v = alphaT4[((size_t)i * T_N + x) * (B_N / 2) + bp];
        *(float2*)&sARe[i * 64 + bp * 2] = make_float2(v.x, v.z);
        *(float2*)&sAIm[i * 64 + bp * 2] = make_float2(v.y, v.w);
    }

    int fx = x - ((x >= 512) ? 1024 : 0);
    float w = (float)fx * W_SCALE;
#pragma unroll
    for (int r = 0; r < 4; ++r) {
        int e = tid + (r << 8);
        int i = e >> 5, o = e & 31;
        int base = (i * COUT + o) * MODES;
        float hr = 0.f, hi = 0.f;
#pragma unroll
        for (int k = 0; k < MODES; ++k) {
            float a = pr[base + k], bI = pim[base + k];
            float d = w - bI;
            float inv = 1.0f / (a * a + d * d);
            float vR = -a * inv, vI = -d * inv;
            float sR = rr[base + k], sI = ri[base + k];
            hr += sR * vR - sI * vI;
            hi += sR * vI + sI * vR;
        }
        Hs[i * 32 + o] = make_float2(hr, hi);
    }
    __syncthreads();

    int o = tid & 31, bg = tid >> 5;
    float accR[8] = {}, accI[8] = {};
#pragma unroll 2
    for (int i = 0; i < CIN; ++i) {
        float2 h = Hs[i * 32 + o];
        float4 ar0 = *(const float4*)&sARe[i * 64 + bg * 8];
        float4 ar1 = *(const float4*)&sARe[i * 64 + bg * 8 + 4];
        float4 ai0 = *(const float4*)&sAIm[i * 64 + bg * 8];
        float4 ai1 = *(const float4*)&sAIm[i * 64 + bg * 8 + 4];
        float aR[8] = {ar0.x, ar0.y, ar0.z, ar0.w, ar1.x, ar1.y, ar1.z, ar1.w};
        float aI[8] = {ai0.x, ai0.y, ai0.z, ai0.w, ai1.x, ai1.y, ai1.z, ai1.w};
#pragma unroll
        for (int bb = 0; bb < 8; ++bb) {
            accR[bb] += aR[bb] * h.x - aI[bb] * h.y;
            accI[bb] += aR[bb] * h.y + aI[bb] * h.x;
        }
    }
#pragma unroll
    for (int bb = 0; bb < 8; ++bb) {
        out1tmp[(size_t)x * 2048 + (bg * 8 + bb) * 32 + o] =
            make_float2(accR[bb], accI[bb]);
    }
}

// ---------------------------------------------------------------------------
// out2 MFMA, R13 addressing (no swizzle) + vectorized B-build:
// thread (bn = tid&63, bh = tid>>6) computes its row's 16B chunk in registers
// and writes 2x ds_write_b128 (balanced banks: start=(20*bn+4*bh)%32).
// partial[chunk=(i*2+xh)][b][n] fp32, 64 chunks.
// ---------------------------------------------------------------------------
#define ABROW 40   /* shorts per LDS row: 32 data + 8 pad (80B) */
__global__ __launch_bounds__(256) void k_out2m(const short* __restrict__ aHi,
                                               const short* __restrict__ aLo,
                                               const float* __restrict__ pr,
                                               const float* __restrict__ pim,
                                               const float* __restrict__ rr,
                                               const float* __restrict__ ri,
                                               float* __restrict__ partial) {
    __shared__ short sAh[64 * ABROW], sAl[64 * ABROW];
    __shared__ short sBh[64 * ABROW], sBl[64 * ABROW];
    __shared__ float sPol[4][32];

    const int nb = blockIdx.x, xh = blockIdx.y, i = blockIdx.z;
    const int tid = threadIdx.x;
    const int w = tid >> 6, l = tid & 63;
    const int r = l & 15, hg = l >> 4;

    if (tid < 32) {
        int o = nb * 2 + (tid >> 4), k = tid & 15;
        int pidx = (i * COUT + o) * MODES + k;
        sPol[0][tid] = pr[pidx]; sPol[1][tid] = pim[pidx];
        sPol[2][tid] = rr[pidx]; sPol[3][tid] = ri[pidx];
    }
    __syncthreads();

    f32x4 acc0 = {0.f, 0.f, 0.f, 0.f};
    f32x4 acc1 = {0.f, 0.f, 0.f, 0.f};
    f32x4 acc2 = {0.f, 0.f, 0.f, 0.f};
    f32x4 acc3 = {0.f, 0.f, 0.f, 0.f};

    const int sb = tid >> 2;                 // A staging row (b)
    const int sc = (tid & 3) * 8;            // A staging col (shorts)
    const size_t abase = ((size_t)sb * CIN + i) * 1024 + (size_t)xh * 512;

    // B-build coords: row bn (= local n), chunk bh
    const int bn = tid & 63, bh = tid >> 6;
    const int bok = bn >> 1, bcomp = bn & 1;
    const float pa = sPol[0][bok], pb = sPol[1][bok];
    const float prr_ = sPol[2][bok], pri_ = sPol[3][bok];

    for (int ks = 0; ks < 16; ++ks) {
        __syncthreads();
        // stage A tile (hi & lo): 64 b x 32 kappa
        *(float4*)&sAh[sb * ABROW + sc] = *(const float4*)&aHi[abase + ks * 32 + sc];
        *(float4*)&sAl[sb * ABROW + sc] = *(const float4*)&aLo[abase + ks * 32 + sc];
        // build B chunk: 4 complex (C1,C2) entries for this row/component
        {
            bf16x8 vh, vl;
#pragma unroll
            for (int j4 = 0; j4 < 4; ++j4) {
                int xl = bh * 4 + j4;
                int xg = xh * 256 + ks * 16 + xl;
                float c1r, c1i, c2r, c2i;
                if (xg == 0) {
                    float s1 = pa * pa + pb * pb;
                    float q1r = pa / s1, q1i = -pb / s1;
                    c1r = prr_ * q1r - pri_ * q1i;
                    c1i = prr_ * q1i + pri_ * q1r;
                    float dr = -pa, di = W_NYQ - pb;
                    float s2 = dr * dr + di * di;
                    float q2r = dr / s2, q2i = -di / s2;
                    c2r = -(prr_ * q2r - pri_ * q2i);
                    c2i = -(prr_ * q2i + pri_ * q2r);
                } else {
                    float wv = (float)xg * W_SCALE;
                    float denr = pa * pa - pb * pb + wv * wv;
                    float deni = 2.0f * pa * pb;
                    float s = denr * denr + deni * deni;
                    float qr = denr / s, qi = -deni / s;
                    float prx = pa * prr_ - pb * pri_;
                    float piy = pa * pri_ + pb * prr_;
                    c1r = 2.0f * (prx * qr - piy * qi);
                    c1i = 2.0f * (prx * qi + piy * qr);
                    float rqr = prr_ * qr - pri_ * qi;
                    float rqi = prr_ * qi + pri_ * qr;
                    c2r = -2.0f * wv * rqr;
                    c2i = -2.0f * wv * rqi;
                }
                float v1 = bcomp ? c1i : c1r;
                float v2 = bcomp ? c2i : c2r;
                short h1, l1, h2, l2;
                bfsplit(v1, &h1, &l1);
                bfsplit(v2, &h2, &l2);
                vh[j4 * 2] = h1; vh[j4 * 2 + 1] = h2;
                vl[j4 * 2] = l1; vl[j4 * 2 + 1] = l2;
            }
            *(bf16x8*)&sBh[bn * ABROW + bh * 8] = vh;
            *(bf16x8*)&sBl[bn * ABROW + bh * 8] = vl;
        }
        __syncthreads();

        bf16x8 bhf = *(bf16x8*)&sBh[(w * 16 + r) * ABROW + hg * 8];
        bf16x8 blf = *(bf16x8*)&sBl[(w * 16 + r) * ABROW + hg * 8];
        {
            bf16x8 ah = *(bf16x8*)&sAh[(0 * 16 + r) * ABROW + hg * 8];
            bf16x8 al = *(bf16x8*)&sAl[(0 * 16 + r) * ABROW + hg * 8];
            acc0 = __builtin_amdgcn_mfma_f32_16x16x32_bf16(ah, bhf, acc0, 0, 0, 0);
            acc0 = __builtin_amdgcn_mfma_f32_16x16x32_bf16(al, bhf, acc0, 0, 0, 0);
            acc0 = __builtin_amdgcn_mfma_f32_16x16x32_bf16(ah, blf, acc0, 0, 0, 0);
        }
        {
            bf16x8 ah = *(bf16x8*)&sAh[(1 * 16 + r) * ABROW + hg * 8];
            bf16x8 al = *(bf16x8*)&sAl[(1 * 16 + r) * ABROW + hg * 8];
            acc1 = __builtin_amdgcn_mfma_f32_16x16x32_bf16(ah, bhf, acc1, 0, 0, 0);
            acc1 = __builtin_amdgcn_mfma_f32_16x16x32_bf16(al, bhf, acc1, 0, 0, 0);
            acc1 = __builtin_amdgcn_mfma_f32_16x16x32_bf16(ah, blf, acc1, 0, 0, 0);
        }
        {
            bf16x8 ah = *(bf16x8*)&sAh[(2 * 16 + r) * ABROW + hg * 8];
            bf16x8 al = *(bf16x8*)&sAl[(2 * 16 + r) * ABROW + hg * 8];
            acc2 = __builtin_amdgcn_mfma_f32_16x16x32_bf16(ah, bhf, acc2, 0, 0, 0);
            acc2 = __builtin_amdgcn_mfma_f32_16x16x32_bf16(al, bhf, acc2, 0, 0, 0);
            acc2 = __builtin_amdgcn_mfma_f32_16x16x32_bf16(ah, blf, acc2, 0, 0, 0);
        }
        {
            bf16x8 ah = *(bf16x8*)&sAh[(3 * 16 + r) * ABROW + hg * 8];
            bf16x8 al = *(bf16x8*)&sAl[(3 * 16 + r) * ABROW + hg * 8];
            acc3 = __builtin_amdgcn_mfma_f32_16x16x32_bf16(ah, bhf, acc3, 0, 0, 0);
            acc3 = __builtin_amdgcn_mfma_f32_16x16x32_bf16(al, bhf, acc3, 0, 0, 0);
            acc3 = __builtin_amdgcn_mfma_f32_16x16x32_bf16(ah, blf, acc3, 0, 0, 0);
        }
    }

    int chunk = i * 2 + xh;
    int n = nb * 64 + w * 16 + r;
    float* dst = partial + (size_t)chunk * (B_N * 1024) + n;
#pragma unroll
    for (int reg = 0; reg < 4; ++reg) {
        dst[(0 * 16 + hg * 4 + reg) * 1024] = acc0[reg];
        dst[(1 * 16 + hg * 4 + reg) * 1024] = acc1[reg];
        dst[(2 * 16 + hg * 4 + reg) * 1024] = acc2[reg];
        dst[(3 * 16 + hg * 4 + reg) * 1024] = acc3[reg];
    }
}

// ---------------------------------------------------------------------------
// reduce 64 partials into split-bf16 A for x2: aXh/aXl[b][ck]
// ---------------------------------------------------------------------------
__global__ __launch_bounds__(256) void k_reduce(const float4* __restrict__ p,
                                                short4* __restrict__ aXh,
                                                short4* __restrict__ aXl,
                                                int nchunk) {
    int f = blockIdx.x * 256 + threadIdx.x;   // 16384 float4s
    float4 s = make_float4(0.f, 0.f, 0.f, 0.f);
    for (int c = 0; c < nchunk; ++c) {
        float4 v = p[(size_t)c * 16384 + f];
        s.x += v.x; s.y += v.y; s.z += v.z; s.w += v.w;
    }
    short4 h, l;
    bfsplit(s.x, &h.x, &l.x);
    bfsplit(s.y, &h.y, &l.y);
    bfsplit(s.z, &h.z, &l.z);
    bfsplit(s.w, &h.w, &l.w);
    aXh[f] = h;
    aXl[f] = l;
}

// ---------------------------------------------------------------------------
// transpose out1tmp[x][bo] -> out1T[bo][x]
// ---------------------------------------------------------------------------
__global__ __launch_bounds__(256) void k_transpose_o1(const float2* __restrict__ out1tmp,
                                                      float2* __restrict__ out1T) {
    __shared__ float2 T[64 * 33];
    int blk = blockIdx.x;
    int bot = blk >> 5, xt = blk & 31;
    int tid = threadIdx.x;
#pragma unroll
    for (int r = 0; r < 8; ++r) {
        int e = tid + (r << 8);
        int j = e & 63, xr = e >> 6;
        T[j * 33 + xr] = out1tmp[((size_t)(xt * 32 + xr)) * 2048 + bot * 64 + j];
    }
    __syncthreads();
#pragma unroll
    for (int r = 0; r < 8; ++r) {
        int e = tid + (r << 8);
        int xx = e & 31, j = e >> 5;
        out1T[((size_t)(bot * 64 + j)) * T_N + xt * 32 + xx] = T[j * 33 + xx];
    }
}

__global__ __launch_bounds__(256) void k_ifft(const float2* __restrict__ out1T,
                                              float* __restrict__ outp) {
    __shared__ float2 A[1024];
    __shared__ float2 Bb[1024];
    __shared__ float2 TW[512];
    int row = blockIdx.x;
    int tid = threadIdx.x;
    build_tw<1>(TW, tid);
    const float2* src = out1T + (size_t)row * T_N;
#pragma unroll
    for (int r = 0; r < 4; ++r) {
        int j = tid + (r << 8);
        A[j] = src[j];
    }
    fft1024<1>(A, Bb, TW, tid);
    float* dst = outp + (size_t)row * T_N;
    const float inv_n = 1.0f / (float)T_N;
#pragma unroll
    for (int r = 0; r < 4; ++r) {
        int j = tid + (r << 8);
        dst[j] = A[j].x * inv_n;
    }
}

// ---------------------------------------------------------------------------
// x2 MFMA, R13 addressing + vectorized B-build. Grid dim3(zb:16, o:32).
// ---------------------------------------------------------------------------
__global__ __launch_bounds__(256) void k_x2m(const short* __restrict__ aXh,
                                             const short* __restrict__ aXl,
                                             const float* __restrict__ pr,
                                             const float* __restrict__ pim,
                                             float* __restrict__ outp) {
    __shared__ short sAh[64 * ABROW], sAl[64 * ABROW];
    __shared__ short sBh[64 * ABROW], sBl[64 * ABROW];
    __shared__ float s_pr[512], s_pim[512];

    const int zb = blockIdx.x, o = blockIdx.y;
    const int tid = threadIdx.x;
    const int w = tid >> 6, l = tid & 63;
    const int r = l & 15, hg = l >> 4;

#pragma unroll
    for (int rr_ = 0; rr_ < 2; ++rr_) {
        int cm = tid + (rr_ << 8);           // 0..511
        int c = cm >> 4, m = cm & 15;
        int pidx = (c * COUT + o) * MODES + m;
        s_pr[cm] = pr[pidx];
        s_pim[cm] = pim[pidx];
    }
    __syncthreads();

    f32x4 acc0 = {0.f, 0.f, 0.f, 0.f};
    f32x4 acc1 = {0.f, 0.f, 0.f, 0.f};
    f32x4 acc2 = {0.f, 0.f, 0.f, 0.f};
    f32x4 acc3 = {0.f, 0.f, 0.f, 0.f};

    const int sb = tid >> 2;                 // A staging row (b)
    const int sc = (tid & 3) * 8;            // A staging col (shorts)
    const float z0f = (float)(zb * 64);

    // B-build coords: row bz (= local z), chunk bh
    const int bz = tid & 63, bh = tid >> 6;
    const float tz = (z0f + (float)bz) * DT;

    for (int ks = 0; ks < 32; ++ks) {
        __syncthreads();
        *(float4*)&sAh[sb * ABROW + sc] = *(const float4*)&aXh[sb * 1024 + ks * 32 + sc];
        *(float4*)&sAl[sb * ABROW + sc] = *(const float4*)&aXl[sb * 1024 + ks * 32 + sc];
        {
            bf16x8 vh, vl;
#pragma unroll
            for (int j4 = 0; j4 < 4; ++j4) {
                int cml = bh * 4 + j4;
                int cm = ks * 16 + cml;
                float gr = s_pr[cm], gi = s_pim[cm];
                float er = __expf(gr * tz);
                float sn, cn;
                __sincosf(gi * tz, &sn, &cn);
                short h1, l1, h2, l2;
                bfsplit(er * cn,  &h1, &l1);
                bfsplit(-er * sn, &h2, &l2);
                vh[j4 * 2] = h1; vh[j4 * 2 + 1] = h2;
                vl[j4 * 2] = l1; vl[j4 * 2 + 1] = l2;
            }
            *(bf16x8*)&sBh[bz * ABROW + bh * 8] = vh;
            *(bf16x8*)&sBl[bz * ABROW + bh * 8] = vl;
        }
        __syncthreads();

        bf16x8 bhf = *(bf16x8*)&sBh[(w * 16 + r) * ABROW + hg * 8];
        bf16x8 blf = *(bf16x8*)&sBl[(w * 16 + r) * ABROW + hg * 8];
        {
            bf16x8 ah = *(bf16x8*)&sAh[(0 * 16 + r) * ABROW + hg * 8];
            bf16x8 al = *(bf16x8*)&sAl[(0 * 16 + r) * ABROW + hg * 8];
            acc0 = __builtin_amdgcn_mfma_f32_16x16x32_bf16(ah, bhf, acc0, 0, 0, 0);
            acc0 = __builtin_amdgcn_mfma_f32_16x16x32_bf16(al, bhf, acc0, 0, 0, 0);
            acc0 = __builtin_amdgcn_mfma_f32_16x16x32_bf16(ah, blf, acc0, 0, 0, 0);
        }
        {
            bf16x8 ah = *(bf16x8*)&sAh[(1 * 16 + r) * ABROW + hg * 8];
            bf16x8 al = *(bf16x8*)&sAl[(1 * 16 + r) * ABROW + hg * 8];
            acc1 = __builtin_amdgcn_mfma_f32_16x16x32_bf16(ah, bhf, acc1, 0, 0, 0);
            acc1 = __builtin_amdgcn_mfma_f32_16x16x32_bf16(al, bhf, acc1, 0, 0, 0);
            acc1 = __builtin_amdgcn_mfma_f32_16x16x32_bf16(ah, blf, acc1, 0, 0, 0);
        }
        {
            bf16x8 ah = *(bf16x8*)&sAh[(2 * 16 + r) * ABROW + hg * 8];
            bf16x8 al = *(bf16x8*)&sAl[(2 * 16 + r) * ABROW + hg * 8];
            acc2 = __builtin_amdgcn_mfma_f32_16x16x32_bf16(ah, bhf, acc2, 0, 0, 0);
            acc2 = __builtin_amdgcn_mfma_f32_16x16x32_bf16(al, bhf, acc2, 0, 0, 0);
            acc2 = __builtin_amdgcn_mfma_f32_16x16x32_bf16(ah, blf, acc2, 0, 0, 0);
        }
        {
            bf16x8 ah = *(bf16x8*)&sAh[(3 * 16 + r) * ABROW + hg * 8];
            bf16x8 al = *(bf16x8*)&sAl[(3 * 16 + r) * ABROW + hg * 8];
            acc3 = __builtin_amdgcn_mfma_f32_16x16x32_bf16(ah, bhf, acc3, 0, 0, 0);
            acc3 = __builtin_amdgcn_mfma_f32_16x16x32_bf16(al, bhf, acc3, 0, 0, 0);
            acc3 = __builtin_amdgcn_mfma_f32_16x16x32_bf16(ah, blf, acc3, 0, 0, 0);
        }
    }

    const float inv_n = 1.0f / (float)T_N;
    size_t base = (size_t)o * T_N + zb * 64 + w * 16 + r;
#pragma unroll
    for (int reg = 0; reg < 4; ++reg) {
        size_t i0 = base + (size_t)(0 * 16 + hg * 4 + reg) * (COUT * T_N);
        size_t i1 = base + (size_t)(1 * 16 + hg * 4 + reg) * (COUT * T_N);
        size_t i2 = base + (size_t)(2 * 16 + hg * 4 + reg) * (COUT * T_N);
        size_t i3 = base + (size_t)(3 * 16 + hg * 4 + reg) * (COUT * T_N);
        outp[i0] += acc0[reg] * inv_n;
        outp[i1] += acc1[reg] * inv_n;
        outp[i2] += acc2[reg] * inv_n;
        outp[i3] += acc3[reg] * inv_n;
    }
}

// ---------------------------------------------------------------------------
extern "C" void kernel_launch(void* const* d_in, const int* in_sizes, int n_in,
                              void* d_out, int out_size, void* d_ws, size_t ws_size,
                              hipStream_t stream) {
    const float* x   = (const float*)d_in[0];
    const float* pr  = (const float*)d_in[2];
    const float* pim = (const float*)d_in[3];
    const float* rr  = (const float*)d_in[4];
    const float* ri  = (const float*)d_in[5];
    float* outp = (float*)d_out;

    char* ws = (char*)d_ws;
    const size_t MB = 1024 * 1024;
    const size_t KB = 1024;
    float2* alpha   = (float2*)ws;                     // [0,16M)
    float2* alphaT  = (float2*)(ws + 16 * MB);         // [16M,32M)
    short*  aXh     = (short*)(ws + 32 * MB);          // [32M,+128K)
    short*  aXl     = (short*)(ws + 32 * MB + 128 * KB); // [+128K,+256K)
    short*  aHi     = (short*)(ws + 33 * MB);          // [33M,37M)
    short*  aLo     = (short*)(ws + 37 * MB);          // [37M,41M)
    float*  o2part;
    if (ws_size >= (size_t)(57 * MB)) {
        o2part = (float*)(ws + 41 * MB);               // [41M,57M): 64 x 256KB
    } else {
        o2part = (float*)ws;                           // region A (alpha dead)
    }
    float2* out1tmp = (float2*)ws;                     // region A (after reduce)
    float2* out1T   = (float2*)(ws + 16 * MB);         // region B (alphaT dead)

    k_fft_fwd     <<<B_N * CIN, 256, 0, stream>>>(x, alpha, aHi, aLo);
    k_transpose_a <<<CIN * 32, 256, 0, stream>>>(alpha, alphaT);
    k_out2m       <<<dim3(16, 2, 32), 256, 0, stream>>>(aHi, aLo,
                                                        pr, pim, rr, ri, o2part);
    k_reduce      <<<64, 256, 0, stream>>>((const float4*)o2part,
                                           (short4*)aXh, (short4*)aXl, 64);
    k_out1        <<<T_N, 256, 0, stream>>>((const float4*)alphaT,
                                            pr, pim, rr, ri, out1tmp);
    k_transpose_o1<<<32 * 32, 256, 0, stream>>>(out1tmp, out1T);
    k_ifft        <<<B_N * COUT, 256, 0, stream>>>(out1T, outp);
    k_x2m         <<<dim3(16, 32), 256, 0, stream>>>(aXh, aXl, pr, pim, outp);
}

// Round 16
// 152.907 us; speedup vs baseline: 1.2671x; 1.0409x over previous
//
#include <hip/hip_runtime.h>

#define T_N   1024
#define B_N   64
#define CIN   32
#define COUT  32
#define MODES 16
#define DT    0.01f
#define PI_F  3.14159265358979323846f
#define W_SCALE 0.613592315154256f   /* 2*pi/(T_N*DT) */
#define W_NYQ  (-314.1592653589793f) /* -pi/DT */

typedef short bf16x8 __attribute__((ext_vector_type(8)));
typedef float f32x4 __attribute__((ext_vector_type(4)));

__device__ __forceinline__ float fastrcp(float x) {
    float r;
    asm("v_rcp_f32 %0, %1" : "=v"(r) : "v"(x));
    return r;
}

// cheap split: truncate hi, truncate lo (pair error <= 2^-16 rel)
__device__ __forceinline__ void bfsplit(float v, short* ph, short* pl) {
    unsigned int u = __float_as_uint(v);
    float lo = v - __uint_as_float(u & 0xFFFF0000u);
    *ph = (short)(u >> 16);
    *pl = (short)(__float_as_uint(lo) >> 16);
}

// ---------------------------------------------------------------------------
// Radix-2 Stockham FFT, length 1024, LDS twiddle table.
// ---------------------------------------------------------------------------
template <int SIGN>
__device__ __forceinline__ void fft1024(float2* A, float2* B, const float2* TW, int tid) {
    float2* src = A;
    float2* dst = B;
    int m = 1;
#pragma unroll
    for (int s = 0; s < 10; ++s) {
        __syncthreads();
#pragma unroll
        for (int r = 0; r < 2; ++r) {
            int idx = tid + (r << 8);
            int k = idx & (m - 1);
            int j = idx >> s;
            float2 c0 = src[k + j * m];
            float2 c1 = src[k + j * m + 512];
            float2 w = TW[(j << s)];
            float ex = c0.x - c1.x, ey = c0.y - c1.y;
            dst[k + 2 * j * m]     = make_float2(c0.x + c1.x, c0.y + c1.y);
            dst[k + 2 * j * m + m] = make_float2(w.x * ex - w.y * ey, w.x * ey + w.y * ex);
        }
        float2* t = src; src = dst; dst = t;
        m <<= 1;
    }
    __syncthreads();
}

template <int SIGN>
__device__ __forceinline__ void build_tw(float2* TW, int tid) {
#pragma unroll
    for (int r = 0; r < 2; ++r) {
        int a = tid + (r << 8);
        float sn, cs;
        __sincosf((float)SIGN * PI_F * (float)a * (1.0f / 512.0f), &sn, &cs);
        TW[a] = make_float2(cs, sn);
    }
}

// ---------------------------------------------------------------------------
// forward FFT + fused split-bf16 conversion.
// ---------------------------------------------------------------------------
__global__ __launch_bounds__(256) void k_fft_fwd(const float* __restrict__ x,
                                                 float2* __restrict__ alpha,
                                                 short* __restrict__ aHi,
                                                 short* __restrict__ aLo) {
    __shared__ float2 A[1024];
    __shared__ float2 Bb[1024];
    __shared__ float2 TW[512];
    int row = blockIdx.x;
    int tid = threadIdx.x;
    build_tw<-1>(TW, tid);
    const float* xr = x + (size_t)row * T_N;
#pragma unroll
    for (int r = 0; r < 4; ++r) {
        int j = tid + (r << 8);
        A[j] = make_float2(xr[j], 0.0f);
    }
    fft1024<-1>(A, Bb, TW, tid);
    float2* outp = alpha + (size_t)row * T_N;
#pragma unroll
    for (int r = 0; r < 4; ++r) {
        int j = tid + (r << 8);
        outp[j] = A[j];
    }
    size_t base = (size_t)row * 1024;
#pragma unroll
    for (int rr_ = 0; rr_ < 2; ++rr_) {
        int xj = tid + (rr_ << 8);        // 0..511
        float2 v = A[xj];
        float aR = v.x;
        float aI = (xj == 0) ? A[512].x : v.y;
        short h0, l0, h1, l1;
        bfsplit(aR, &h0, &l0);
        bfsplit(aI, &h1, &l1);
        aHi[base + xj * 2]     = h0;
        aHi[base + xj * 2 + 1] = h1;
        aLo[base + xj * 2]     = l0;
        aLo[base + xj * 2 + 1] = l1;
    }
}

// ---------------------------------------------------------------------------
// transpose alpha[(b*CIN+i)][x] -> alphaT[i][x][b]   (feeds k_out1 only)
// ---------------------------------------------------------------------------
__global__ __launch_bounds__(256) void k_transpose_a(const float2* __restrict__ alpha,
                                                     float2* __restrict__ alphaT) {
    __shared__ float2 T[32 * 66];
    int blk = blockIdx.x;
    int i = blk >> 5, xt = blk & 31;
    int tid = threadIdx.x;
#pragma unroll
    for (int r = 0; r < 8; ++r) {
        int e = tid + (r << 8);
        int xx = e & 31, b = e >> 5;
        T[xx * 66 + b] = alpha[((size_t)(b * CIN + i)) * T_N + xt * 32 + xx];
    }
    __syncthreads();
#pragma unroll
    for (int r = 0; r < 8; ++r) {
        int e = tid + (r << 8);
        int b = e & 63, xx = e >> 6;
        alphaT[((size_t)i * T_N + xt * 32 + xx) * B_N + b] = T[xx * 66 + b];
    }
}

// ---------------------------------------------------------------------------
// out1: per-frequency mixing; fastrcp in Hsum build.
// ---------------------------------------------------------------------------
__global__ __launch_bounds__(256) void k_out1(const float4* __restrict__ alphaT4,
                                              const float* __restrict__ pr,
                                              const float* __restrict__ pim,
                                              const float* __restrict__ rr,
                                              const float* __restrict__ ri,
                                              float2* __restrict__ out1tmp) {
    __shared__ float sARe[32 * 64];
    __shared__ float sAIm[32 * 64];
    __shared__ float2 Hs[32 * 32];
    int x = blockIdx.x;
    int tid = threadIdx.x;

#pragma unroll
    for (int r = 0; r < 4; ++r) {
        int e = tid + (r << 8);
        int i = e >> 5, bp = e & 31;
        float4 v = alphaT4[((size_t)i * T_N + x) * (B_N / 2) + bp];
        *(float2*)&sARe[i * 64 + bp * 2] = make_float2(v.x, v.z);
        *(float2*)&sAIm[i * 64 + bp * 2] = make_float2(v.y, v.w);
    }

    int fx = x - ((x >= 512) ? 1024 : 0);
    float w = (float)fx * W_SCALE;
#pragma unroll
    for (int r = 0; r < 4; ++r) {
        int e = tid + (r << 8);
        int i = e >> 5, o = e & 31;
        int base = (i * COUT + o) * MODES;
        float hr = 0.f, hi = 0.f;
#pragma unroll
        for (int k = 0; k < MODES; ++k) {
            float a = pr[base + k], bI = pim[base + k];
            float d = w - bI;
            float inv = fastrcp(fmaf(d, d, a * a));
            float vR = -a * inv, vI = -d * inv;
            float sR = rr[base + k], sI = ri[base + k];
            hr += sR * vR - sI * vI;
            hi += sR * vI + sI * vR;
        }
        Hs[i * 32 + o] = make_float2(hr, hi);
    }
    __syncthreads();

    int o = tid & 31, bg = tid >> 5;
    float accR[8] = {}, accI[8] = {};
#pragma unroll 2
    for (int i = 0; i < CIN; ++i) {
        float2 h = Hs[i * 32 + o];
        float4 ar0 = *(const float4*)&sARe[i * 64 + bg * 8];
        float4 ar1 = *(const float4*)&sARe[i * 64 + bg * 8 + 4];
        float4 ai0 = *(const float4*)&sAIm[i * 64 + bg * 8];
        float4 ai1 = *(const float4*)&sAIm[i * 64 + bg * 8 + 4];
        float aR[8] = {ar0.x, ar0.y, ar0.z, ar0.w, ar1.x, ar1.y, ar1.z, ar1.w};
        float aI[8] = {ai0.x, ai0.y, ai0.z, ai0.w, ai1.x, ai1.y, ai1.z, ai1.w};
#pragma unroll
        for (int bb = 0; bb < 8; ++bb) {
            accR[bb] += aR[bb] * h.x - aI[bb] * h.y;
            accI[bb] += aR[bb] * h.y + aI[bb] * h.x;
        }
    }
#pragma unroll
    for (int bb = 0; bb < 8; ++bb) {
        out1tmp[(size_t)x * 2048 + (bg * 8 + bb) * 32 + o] =
            make_float2(accR[bb], accI[bb]);
    }
}

// ---------------------------------------------------------------------------
// out2 MFMA, vectorized B-build with hoisted per-thread constants + fastrcp.
// partial[chunk=(i*2+xh)][b][n] fp32, 64 chunks.
// ---------------------------------------------------------------------------
#define ABROW 40   /* shorts per LDS row: 32 data + 8 pad (80B) */
__global__ __launch_bounds__(256) void k_out2m(const short* __restrict__ aHi,
                                               const short* __restrict__ aLo,
                                               const float* __restrict__ pr,
                                               const float* __restrict__ pim,
                                               const float* __restrict__ rr,
                                               const float* __restrict__ ri,
                                               float* __restrict__ partial) {
    __shared__ short sAh[64 * ABROW], sAl[64 * ABROW];
    __shared__ short sBh[64 * ABROW], sBl[64 * ABROW];
    __shared__ float sPol[4][32];

    const int nb = blockIdx.x, xh = blockIdx.y, i = blockIdx.z;
    const int tid = threadIdx.x;
    const int w = tid >> 6, l = tid & 63;
    const int r = l & 15, hg = l >> 4;

    if (tid < 32) {
        int o = nb * 2 + (tid >> 4), k = tid & 15;
        int pidx = (i * COUT + o) * MODES + k;
        sPol[0][tid] = pr[pidx]; sPol[1][tid] = pim[pidx];
        sPol[2][tid] = rr[pidx]; sPol[3][tid] = ri[pidx];
    }
    __syncthreads();

    f32x4 acc0 = {0.f, 0.f, 0.f, 0.f};
    f32x4 acc1 = {0.f, 0.f, 0.f, 0.f};
    f32x4 acc2 = {0.f, 0.f, 0.f, 0.f};
    f32x4 acc3 = {0.f, 0.f, 0.f, 0.f};

    const int sb = tid >> 2;                 // A staging row (b)
    const int sc = (tid & 3) * 8;            // A staging col (shorts)
    const size_t abase = ((size_t)sb * CIN + i) * 1024 + (size_t)xh * 512;

    // B-build coords + hoisted constants
    const int bn = tid & 63, bh = tid >> 6;
    const int bok = bn >> 1, bcomp = bn & 1;
    const float pa = sPol[0][bok], pb = sPol[1][bok];
    const float prr_ = sPol[2][bok], pri_ = sPol[3][bok];
    const float K_d  = pa * pa - pb * pb;
    const float mKe  = -2.0f * pa * pb;                 // -deni
    const float K_e2 = (2.0f * pa * pb) * (2.0f * pa * pb);
    const float prx2 = 2.0f * (pa * prr_ - pb * pri_);
    const float piy2 = 2.0f * (pa * pri_ + pb * prr_);
    const float A1 = bcomp ? piy2 : prx2;
    const float B1 = bcomp ? prx2 : -piy2;
    const float A2 = bcomp ? pri_ : prr_;
    const float B2 = bcomp ? prr_ : -pri_;

    for (int ks = 0; ks < 16; ++ks) {
        __syncthreads();
        // stage A tile (hi & lo): 64 b x 32 kappa
        *(float4*)&sAh[sb * ABROW + sc] = *(const float4*)&aHi[abase + ks * 32 + sc];
        *(float4*)&sAl[sb * ABROW + sc] = *(const float4*)&aLo[abase + ks * 32 + sc];
        // build B chunk: 4 entries for this row/component
        {
            bf16x8 vh, vl;
#pragma unroll
            for (int j4 = 0; j4 < 4; ++j4) {
                int xl = bh * 4 + j4;
                int xg = xh * 256 + ks * 16 + xl;
                float v1, v2;
                if (xg == 0) {
                    float s1 = pa * pa + pb * pb;
                    float q1r = pa / s1, q1i = -pb / s1;
                    float c1r = prr_ * q1r - pri_ * q1i;
                    float c1i = prr_ * q1i + pri_ * q1r;
                    float dr = -pa, di = W_NYQ - pb;
                    float s2 = dr * dr + di * di;
                    float q2r = dr / s2, q2i = -di / s2;
                    float c2r = -(prr_ * q2r - pri_ * q2i);
                    float c2i = -(prr_ * q2i + pri_ * q2r);
                    v1 = bcomp ? c1i : c1r;
                    v2 = bcomp ? c2i : c2r;
                } else {
                    float wv = (float)xg * W_SCALE;
                    float denr = fmaf(wv, wv, K_d);
                    float s = fmaf(denr, denr, K_e2);
                    float inv = fastrcp(s);
                    float qr = denr * inv, qi = mKe * inv;
                    v1 = A1 * qr + B1 * qi;
                    float rq = A2 * qr + B2 * qi;
                    v2 = -2.0f * wv * rq;
                }
                short h1, l1, h2, l2;
                bfsplit(v1, &h1, &l1);
                bfsplit(v2, &h2, &l2);
                vh[j4 * 2] = h1; vh[j4 * 2 + 1] = h2;
                vl[j4 * 2] = l1; vl[j4 * 2 + 1] = l2;
            }
            *(bf16x8*)&sBh[bn * ABROW + bh * 8] = vh;
            *(bf16x8*)&sBl[bn * ABROW + bh * 8] = vl;
        }
        __syncthreads();

        bf16x8 bhf = *(bf16x8*)&sBh[(w * 16 + r) * ABROW + hg * 8];
        bf16x8 blf = *(bf16x8*)&sBl[(w * 16 + r) * ABROW + hg * 8];
        {
            bf16x8 ah = *(bf16x8*)&sAh[(0 * 16 + r) * ABROW + hg * 8];
            bf16x8 al = *(bf16x8*)&sAl[(0 * 16 + r) * ABROW + hg * 8];
            acc0 = __builtin_amdgcn_mfma_f32_16x16x32_bf16(ah, bhf, acc0, 0, 0, 0);
            acc0 = __builtin_amdgcn_mfma_f32_16x16x32_bf16(al, bhf, acc0, 0, 0, 0);
            acc0 = __builtin_amdgcn_mfma_f32_16x16x32_bf16(ah, blf, acc0, 0, 0, 0);
        }
        {
            bf16x8 ah = *(bf16x8*)&sAh[(1 * 16 + r) * ABROW + hg * 8];
            bf16x8 al = *(bf16x8*)&sAl[(1 * 16 + r) * ABROW + hg * 8];
            acc1 = __builtin_amdgcn_mfma_f32_16x16x32_bf16(ah, bhf, acc1, 0, 0, 0);
            acc1 = __builtin_amdgcn_mfma_f32_16x16x32_bf16(al, bhf, acc1, 0, 0, 0);
            acc1 = __builtin_amdgcn_mfma_f32_16x16x32_bf16(ah, blf, acc1, 0, 0, 0);
        }
        {
            bf16x8 ah = *(bf16x8*)&sAh[(2 * 16 + r) * ABROW + hg * 8];
            bf16x8 al = *(bf16x8*)&sAl[(2 * 16 + r) * ABROW + hg * 8];
            acc2 = __builtin_amdgcn_mfma_f32_16x16x32_bf16(ah, bhf, acc2, 0, 0, 0);
            acc2 = __builtin_amdgcn_mfma_f32_16x16x32_bf16(al, bhf, acc2, 0, 0, 0);
            acc2 = __builtin_amdgcn_mfma_f32_16x16x32_bf16(ah, blf, acc2, 0, 0, 0);
        }
        {
            bf16x8 ah = *(bf16x8*)&sAh[(3 * 16 + r) * ABROW + hg * 8];
            bf16x8 al = *(bf16x8*)&sAl[(3 * 16 + r) * ABROW + hg * 8];
            acc3 = __builtin_amdgcn_mfma_f32_16x16x32_bf16(ah, bhf, acc3, 0, 0, 0);
            acc3 = __builtin_amdgcn_mfma_f32_16x16x32_bf16(al, bhf, acc3, 0, 0, 0);
            acc3 = __builtin_amdgcn_mfma_f32_16x16x32_bf16(ah, blf, acc3, 0, 0, 0);
        }
    }

    int chunk = i * 2 + xh;
    int n = nb * 64 + w * 16 + r;
    float* dst = partial + (size_t)chunk * (B_N * 1024) + n;
#pragma unroll
    for (int reg = 0; reg < 4; ++reg) {
        dst[(0 * 16 + hg * 4 + reg) * 1024] = acc0[reg];
        dst[(1 * 16 + hg * 4 + reg) * 1024] = acc1[reg];
        dst[(2 * 16 + hg * 4 + reg) * 1024] = acc2[reg];
        dst[(3 * 16 + hg * 4 + reg) * 1024] = acc3[reg];
    }
}

// ---------------------------------------------------------------------------
// reduce 64 partials into split-bf16 A for x2: aXh/aXl[b][ck]
// ---------------------------------------------------------------------------
__global__ __launch_bounds__(256) void k_reduce(const float4* __restrict__ p,
                                                short4* __restrict__ aXh,
                                                short4* __restrict__ aXl,
                                                int nchunk) {
    int f = blockIdx.x * 256 + threadIdx.x;   // 16384 float4s
    float4 s = make_float4(0.f, 0.f, 0.f, 0.f);
    for (int c = 0; c < nchunk; ++c) {
        float4 v = p[(size_t)c * 16384 + f];
        s.x += v.x; s.y += v.y; s.z += v.z; s.w += v.w;
    }
    short4 h, l;
    bfsplit(s.x, &h.x, &l.x);
    bfsplit(s.y, &h.y, &l.y);
    bfsplit(s.z, &h.z, &l.z);
    bfsplit(s.w, &h.w, &l.w);
    aXh[f] = h;
    aXl[f] = l;
}

// ---------------------------------------------------------------------------
// transpose out1tmp[x][bo] -> out1T[bo][x]
// ---------------------------------------------------------------------------
__global__ __launch_bounds__(256) void k_transpose_o1(const float2* __restrict__ out1tmp,
                                                      float2* __restrict__ out1T) {
    __shared__ float2 T[64 * 33];
    int blk = blockIdx.x;
    int bot = blk >> 5, xt = blk & 31;
    int tid = threadIdx.x;
#pragma unroll
    for (int r = 0; r < 8; ++r) {
        int e = tid + (r << 8);
        int j = e & 63, xr = e >> 6;
        T[j * 33 + xr] = out1tmp[((size_t)(xt * 32 + xr)) * 2048 + bot * 64 + j];
    }
    __syncthreads();
#pragma unroll
    for (int r = 0; r < 8; ++r) {
        int e = tid + (r << 8);
        int xx = e & 31, j = e >> 5;
        out1T[((size_t)(bot * 64 + j)) * T_N + xt * 32 + xx] = T[j * 33 + xx];
    }
}

__global__ __launch_bounds__(256) void k_ifft(const float2* __restrict__ out1T,
                                              float* __restrict__ outp) {
    __shared__ float2 A[1024];
    __shared__ float2 Bb[1024];
    __shared__ float2 TW[512];
    int row = blockIdx.x;
    int tid = threadIdx.x;
    build_tw<1>(TW, tid);
    const float2* src = out1T + (size_t)row * T_N;
#pragma unroll
    for (int r = 0; r < 4; ++r) {
        int j = tid + (r << 8);
        A[j] = src[j];
    }
    fft1024<1>(A, Bb, TW, tid);
    float* dst = outp + (size_t)row * T_N;
    const float inv_n = 1.0f / (float)T_N;
#pragma unroll
    for (int r = 0; r < 4; ++r) {
        int j = tid + (r << 8);
        dst[j] = A[j].x * inv_n;
    }
}

// ---------------------------------------------------------------------------
// x2 MFMA, vectorized B-build. Grid dim3(zb:16, o:32).
// ---------------------------------------------------------------------------
__global__ __launch_bounds__(256) void k_x2m(const short* __restrict__ aXh,
                                             const short* __restrict__ aXl,
                                             const float* __restrict__ pr,
                                             const float* __restrict__ pim,
                                             float* __restrict__ outp) {
    __shared__ short sAh[64 * ABROW], sAl[64 * ABROW];
    __shared__ short sBh[64 * ABROW], sBl[64 * ABROW];
    __shared__ float s_pr[512], s_pim[512];

    const int zb = blockIdx.x, o = blockIdx.y;
    const int tid = threadIdx.x;
    const int w = tid >> 6, l = tid & 63;
    const int r = l & 15, hg = l >> 4;

#pragma unroll
    for (int rr_ = 0; rr_ < 2; ++rr_) {
        int cm = tid + (rr_ << 8);           // 0..511
        int c = cm >> 4, m = cm & 15;
        int pidx = (c * COUT + o) * MODES + m;
        s_pr[cm] = pr[pidx];
        s_pim[cm] = pim[pidx];
    }
    __syncthreads();

    f32x4 acc0 = {0.f, 0.f, 0.f, 0.f};
    f32x4 acc1 = {0.f, 0.f, 0.f, 0.f};
    f32x4 acc2 = {0.f, 0.f, 0.f, 0.f};
    f32x4 acc3 = {0.f, 0.f, 0.f, 0.f};

    const int sb = tid >> 2;                 // A staging row (b)
    const int sc = (tid & 3) * 8;            // A staging col (shorts)
    const float z0f = (float)(zb * 64);

    // B-build coords: row bz (= local z), chunk bh
    const int bz = tid & 63, bh = tid >> 6;
    const float tz = (z0f + (float)bz) * DT;

    for (int ks = 0; ks < 32; ++ks) {
        __syncthreads();
        *(float4*)&sAh[sb * ABROW + sc] = *(const float4*)&aXh[sb * 1024 + ks * 32 + sc];
        *(float4*)&sAl[sb * ABROW + sc] = *(const float4*)&aXl[sb * 1024 + ks * 32 + sc];
        {
            bf16x8 vh, vl;
#pragma unroll
            for (int j4 = 0; j4 < 4; ++j4) {
                int cml = bh * 4 + j4;
                int cm = ks * 16 + cml;
                float gr = s_pr[cm], gi = s_pim[cm];
                float er = __expf(gr * tz);
                float sn, cn;
                __sincosf(gi * tz, &sn, &cn);
                short h1, l1, h2, l2;
                bfsplit(er * cn,  &h1, &l1);
                bfsplit(-er * sn, &h2, &l2);
                vh[j4 * 2] = h1; vh[j4 * 2 + 1] = h2;
                vl[j4 * 2] = l1; vl[j4 * 2 + 1] = l2;
            }
            *(bf16x8*)&sBh[bz * ABROW + bh * 8] = vh;
            *(bf16x8*)&sBl[bz * ABROW + bh * 8] = vl;
        }
        __syncthreads();

        bf16x8 bhf = *(bf16x8*)&sBh[(w * 16 + r) * ABROW + hg * 8];
        bf16x8 blf = *(bf16x8*)&sBl[(w * 16 + r) * ABROW + hg * 8];
        {
            bf16x8 ah = *(bf16x8*)&sAh[(0 * 16 + r) * ABROW + hg * 8];
            bf16x8 al = *(bf16x8*)&sAl[(0 * 16 + r) * ABROW + hg * 8];
            acc0 = __builtin_amdgcn_mfma_f32_16x16x32_bf16(ah, bhf, acc0, 0, 0, 0);
            acc0 = __builtin_amdgcn_mfma_f32_16x16x32_bf16(al, bhf, acc0, 0, 0, 0);
            acc0 = __builtin_amdgcn_mfma_f32_16x16x32_bf16(ah, blf, acc0, 0, 0, 0);
        }
        {
            bf16x8 ah = *(bf16x8*)&sAh[(1 * 16 + r) * ABROW + hg * 8];
            bf16x8 al = *(bf16x8*)&sAl[(1 * 16 + r) * ABROW + hg * 8];
            acc1 = __builtin_amdgcn_mfma_f32_16x16x32_bf16(ah, bhf, acc1, 0, 0, 0);
            acc1 = __builtin_amdgcn_mfma_f32_16x16x32_bf16(al, bhf, acc1, 0, 0, 0);
            acc1 = __builtin_amdgcn_mfma_f32_16x16x32_bf16(ah, blf, acc1, 0, 0, 0);
        }
        {
            bf16x8 ah = *(bf16x8*)&sAh[(2 * 16 + r) * ABROW + hg * 8];
            bf16x8 al = *(bf16x8*)&sAl[(2 * 16 + r) * ABROW + hg * 8];
            acc2 = __builtin_amdgcn_mfma_f32_16x16x32_bf16(ah, bhf, acc2, 0, 0, 0);
            acc2 = __builtin_amdgcn_mfma_f32_16x16x32_bf16(al, bhf, acc2, 0, 0, 0);
            acc2 = __builtin_amdgcn_mfma_f32_16x16x32_bf16(ah, blf, acc2, 0, 0, 0);
        }
        {
            bf16x8 ah = *(bf16x8*)&sAh[(3 * 16 + r) * ABROW + hg * 8];
            bf16x8 al = *(bf16x8*)&sAl[(3 * 16 + r) * ABROW + hg * 8];
            acc3 = __builtin_amdgcn_mfma_f32_16x16x32_bf16(ah, bhf, acc3, 0, 0, 0);
            acc3 = __builtin_amdgcn_mfma_f32_16x16x32_bf16(al, bhf, acc3, 0, 0, 0);
            acc3 = __builtin_amdgcn_mfma_f32_16x16x32_bf16(ah, blf, acc3, 0, 0, 0);
        }
    }

    const float inv_n = 1.0f / (float)T_N;
    size_t base = (size_t)o * T_N + zb * 64 + w * 16 + r;
#pragma unroll
    for (int reg = 0; reg < 4; ++reg) {
        size_t i0 = base + (size_t)(0 * 16 + hg * 4 + reg) * (COUT * T_N);
        size_t i1 = base + (size_t)(1 * 16 + hg * 4 + reg) * (COUT * T_N);
        size_t i2 = base + (size_t)(2 * 16 + hg * 4 + reg) * (COUT * T_N);
        size_t i3 = base + (size_t)(3 * 16 + hg * 4 + reg) * (COUT * T_N);
        outp[i0] += acc0[reg] * inv_n;
        outp[i1] += acc1[reg] * inv_n;
        outp[i2] += acc2[reg] * inv_n;
        outp[i3] += acc3[reg] * inv_n;
    }
}

// ---------------------------------------------------------------------------
extern "C" void kernel_launch(void* const* d_in, const int* in_sizes, int n_in,
                              void* d_out, int out_size, void* d_ws, size_t ws_size,
                              hipStream_t stream) {
    const float* x   = (const float*)d_in[0];
    const float* pr  = (const float*)d_in[2];
    const float* pim = (const float*)d_in[3];
    const float* rr  = (const float*)d_in[4];
    const float* ri  = (const float*)d_in[5];
    float* outp = (float*)d_out;

    char* ws = (char*)d_ws;
    const size_t MB = 1024 * 1024;
    const size_t KB = 1024;
    float2* alpha   = (float2*)ws;                     // [0,16M)
    float2* alphaT  = (float2*)(ws + 16 * MB);         // [16M,32M)
    short*  aXh     = (short*)(ws + 32 * MB);          // [32M,+128K)
    short*  aXl     = (short*)(ws + 32 * MB + 128 * KB); // [+128K,+256K)
    short*  aHi     = (short*)(ws + 33 * MB);          // [33M,37M)
    short*  aLo     = (short*)(ws + 37 * MB);          // [37M,41M)
    float*  o2part;
    if (ws_size >= (size_t)(57 * MB)) {
        o2part = (float*)(ws + 41 * MB);               // [41M,57M): 64 x 256KB
    } else {
        o2part = (float*)ws;                           // region A (alpha dead)
    }
    float2* out1tmp = (float2*)ws;                     // region A (after reduce)
    float2* out1T   = (float2*)(ws + 16 * MB);         // region B (alphaT dead)

    k_fft_fwd     <<<B_N * CIN, 256, 0, stream>>>(x, alpha, aHi, aLo);
    k_transpose_a <<<CIN * 32, 256, 0, stream>>>(alpha, alphaT);
    k_out2m       <<<dim3(16, 2, 32), 256, 0, stream>>>(aHi, aLo,
                                                        pr, pim, rr, ri, o2part);
    k_reduce      <<<64, 256, 0, stream>>>((const float4*)o2part,
                                           (short4*)aXh, (short4*)aXl, 64);
    k_out1        <<<T_N, 256, 0, stream>>>((const float4*)alphaT,
                                            pr, pim, rr, ri, out1tmp);
    k_transpose_o1<<<32 * 32, 256, 0, stream>>>(out1tmp, out1T);
    k_ifft        <<<B_N * COUT, 256, 0, stream>>>(out1T, outp);
    k_x2m         <<<dim3(16, 32), 256, 0, stream>>>(aXh, aXl, pr, pim, outp);
}